// Round 12
// baseline (375.554 us; speedup 1.0000x reference)
//
#include <hip/hip_runtime.h>
#include <hip/hip_bf16.h>

#define H 8
#define C 16
#define HC 128          // H*C
#define NEG 0.2f
#define XS_S 132        // LDS row stride (floats) for k1 x-tile

#define ANSH 6          // 64 nodes per fine aggregation bucket
#define AN 64
#define AMSK 63
#define CAP2 2560       // pairs2 capacity per fine bucket (mean 2048, +11 sigma)
#define MAXB2 2048      // fine bucket cap: N <= 131072
#define CB_SH 12        // 4096 nodes per coarse bucket
#define CBMSK 4095
#define MAXB1 64        // coarse bucket cap (src packs in 17b: N <= 131072)
#define EPB 4096        // edges per binning chunk (16 KB LDS staging; 256-thr
                        // blocks -> 7-8 blocks/CU instead of 1.5 at 8192/512)

// exact: for x>=0 max returns x, for x<0 returns 0.2x  (2 VALU, no cndmask)
__device__ __forceinline__ float lrelu(float x) { return fmaxf(x, NEG * x); }

__device__ __forceinline__ unsigned pack_bf16(float a, float b) {
    union { __hip_bfloat16 h; unsigned short u; } ua, ub;
    ua.h = __float2bfloat16(a);
    ub.h = __float2bfloat16(b);
    return (unsigned)ua.u | ((unsigned)ub.u << 16);
}
__device__ __forceinline__ float bf_lo(unsigned d) { return __uint_as_float(d << 16); }
__device__ __forceinline__ float bf_hi(unsigned d) { return __uint_as_float(d & 0xffff0000u); }

// K1: h = x @ W, fp32 register-tiled GEMM, bf16-packed output (R9 version).
// Epilogue also computes a_src/a_dst (width-4 shfl reduce).
__global__ void __launch_bounds__(256) k1_gemm(const float* __restrict__ x,
                                               const float* __restrict__ W,
                                               const float* __restrict__ att_src,
                                               const float* __restrict__ att_dst,
                                               unsigned* __restrict__ h16,
                                               float* __restrict__ a_src,
                                               float* __restrict__ a_dst, int N) {
    __shared__ float xs[64 * XS_S];
    const int n0 = blockIdx.x * 64;
    const int t = threadIdx.x;
#pragma unroll
    for (int i = 0; i < 8; ++i) {
        int id = t + 256 * i;           // 2048 float4-chunks
        int r = id >> 5, kq = id & 31;
        int n = n0 + r;
        float4 v = (n < N) ? ((const float4*)x)[(size_t)n * 32 + kq]
                           : make_float4(0.f, 0.f, 0.f, 0.f);
        *(float4*)&xs[r * XS_S + kq * 4] = v;
    }
    __syncthreads();
    const int cg = t & 31;        // cols cg*4..+3
    const int r0 = (t >> 5) * 8;  // rows r0..r0+7
    float acc[8][4];
#pragma unroll
    for (int i = 0; i < 8; ++i)
#pragma unroll
        for (int j = 0; j < 4; ++j) acc[i][j] = 0.f;

#pragma unroll 4
    for (int k = 0; k < HC; ++k) {
        const float4 wv = ((const float4*)W)[k * 32 + cg];
        float wr[4] = {wv.x, wv.y, wv.z, wv.w};
#pragma unroll
        for (int i = 0; i < 8; ++i) {
            float xv = xs[(r0 + i) * XS_S + k];   // broadcast across cg lanes
#pragma unroll
            for (int j = 0; j < 4; ++j) acc[i][j] += xv * wr[j];
        }
    }
    const int fhd = cg >> 2;       // head owning this lane's 4 cols
    const int cq  = cg & 3;        // quarter within the head's 16 cols
#pragma unroll
    for (int i = 0; i < 8; ++i) {
        int n = n0 + r0 + i;
        if (n < N) {
            uint2 dv = make_uint2(pack_bf16(acc[i][0], acc[i][1]),
                                  pack_bf16(acc[i][2], acc[i][3]));
            *(uint2*)&h16[(size_t)n * 64 + cg * 2] = dv;
        }
        float ps = 0.f, pd = 0.f;
#pragma unroll
        for (int jj = 0; jj < 4; ++jj) {
            float hv = acc[i][jj];
            ps += hv * att_src[fhd * C + cq * 4 + jj];
            pd += hv * att_dst[fhd * C + cq * 4 + jj];
        }
        ps += __shfl_xor(ps, 1, 4); pd += __shfl_xor(pd, 1, 4);
        ps += __shfl_xor(ps, 2, 4); pd += __shfl_xor(pd, 2, 4);
        if (cq == 0 && n < N) {
            a_src[(unsigned)n * 8u + fhd] = ps;
            a_dst[(unsigned)n * 8u + fhd] = pd;
        }
    }
}

// KB_BIN1: coarse binning (25 buckets of 4096 nodes). 256-thread blocks,
// 4096-edge chunks: ~19 KB LDS -> 7-8 blocks/CU (the 512/8192 version ran
// at 1.5 blocks/CU and was latency-bound across its barrier phases).
// Wave-split histograms/cursors ([4] waves). Runs ~164 edges = 656 B.
// Pack: src(17b) | (dst & 4095) << 17.
__global__ void __launch_bounds__(256) kb_bin1(const int* __restrict__ ei,
                                               int* __restrict__ gcount1,
                                               unsigned* __restrict__ pairs1,
                                               int E, int NB1, int cap1) {
    __shared__ unsigned sp[EPB];       // 16 KB
    __shared__ int hist[4][MAXB1];     // per-wave histograms
    __shared__ int cur[4][MAXB1];      // per-(wave,bucket) cursors
    __shared__ int tot[MAXB1];
    __shared__ int scn[MAXB1];
    __shared__ int gbase[MAXB1];
    const int t = threadIdx.x;
    const int wv = t >> 6;
    const int e0 = blockIdx.x * EPB;
    const int nE = min(EPB, E - e0);
    for (int i = t; i < 4 * MAXB1; i += 256) ((int*)hist)[i] = 0;
    __syncthreads();

    const bool v4 = ((E & 3) == 0) && ((nE & 3) == 0);
    const int nE4 = nE >> 2;
    const int4* d4p = (const int4*)(ei + E + e0);
    const int4* s4p = (const int4*)(ei + e0);
    if (v4) {
        for (int i = t; i < nE4; i += 256) {
            int4 d = d4p[i];
            atomicAdd(&hist[wv][d.x >> CB_SH], 1);
            atomicAdd(&hist[wv][d.y >> CB_SH], 1);
            atomicAdd(&hist[wv][d.z >> CB_SH], 1);
            atomicAdd(&hist[wv][d.w >> CB_SH], 1);
        }
    } else {
        for (int i = t; i < nE; i += 256)
            atomicAdd(&hist[wv][ei[E + e0 + i] >> CB_SH], 1);
    }
    __syncthreads();
    if (t < MAXB1) {
        int s = 0;
#pragma unroll
        for (int w = 0; w < 4; ++w) s += hist[w][t];
        tot[t] = s;
        scn[t] = s;
    }
    __syncthreads();
    for (int off = 1; off < MAXB1; off <<= 1) {
        int v = (t < MAXB1 && t >= off) ? scn[t - off] : 0;
        __syncthreads();
        if (t < MAXB1) scn[t] += v;
        __syncthreads();
    }
    if (t < MAXB1) {
        int h = tot[t];
        gbase[t] = h ? t * cap1 + atomicAdd(&gcount1[t], h) : 0;
        int off = scn[t] - h;              // exclusive start in sp
#pragma unroll
        for (int w = 0; w < 4; ++w) { cur[w][t] = off; off += hist[w][t]; }
    }
    __syncthreads();
    if (v4) {
        for (int i = t; i < nE4; i += 256) {
            int4 d = d4p[i];
            int4 sv = s4p[i];
#pragma unroll
            for (int q = 0; q < 4; ++q) {
                int dst = (&d.x)[q], src = (&sv.x)[q];
                int pos = atomicAdd(&cur[wv][dst >> CB_SH], 1);
                sp[pos] = (unsigned)src | ((unsigned)(dst & CBMSK) << 17);
            }
        }
    } else {
        for (int i = t; i < nE; i += 256) {
            int dst = ei[E + e0 + i], src = ei[e0 + i];
            int pos = atomicAdd(&cur[wv][dst >> CB_SH], 1);
            sp[pos] = (unsigned)src | ((unsigned)(dst & CBMSK) << 17);
        }
    }
    __syncthreads();
    const int lane = t & 63;
    for (int i = wv; i < NB1; i += 4) {
        int end = scn[i];
        int st  = (i > 0) ? scn[i - 1] : 0;
        int len = end - st;
        if (len <= 0) continue;
        int gb = gbase[i];
        int rem = i * cap1 + cap1 - gb;
        int wl = min(len, max(rem, 0));
        for (int k = lane; k < wl; k += 64)
            pairs1[gb + k] = sp[st + k];
    }
}

// KB_BIN2: fine binning within a coarse region. Same 256-thread/4096-edge
// high-occupancy structure. Runs 4096/64 = 64 edges = 256 B (4 lines).
// Repack to src | ldst6<<18.
__global__ void __launch_bounds__(256) kb_bin2(const unsigned* __restrict__ pairs1,
                                               const int* __restrict__ gcount1,
                                               int* __restrict__ gcount2,
                                               unsigned* __restrict__ pairs2,
                                               int cap1, int ch2) {
    __shared__ unsigned sp[EPB];       // 16 KB
    __shared__ int hist[4][64];
    __shared__ int cur[4][64];
    __shared__ int tot[64];
    __shared__ int scn[64];
    __shared__ int gbase[64];
    const int cb = blockIdx.x / ch2;
    const int ci = blockIdx.x % ch2;
    const int c1 = min(gcount1[cb], cap1);
    const int e0 = ci * EPB;
    if (e0 >= c1) return;                  // uniform exit
    const int nE = min(EPB, c1 - e0);
    const unsigned b1 = (unsigned)cb * (unsigned)cap1 + (unsigned)e0;
    const int t = threadIdx.x;
    const int wv = t >> 6;
    for (int i = t; i < 4 * 64; i += 256) ((int*)hist)[i] = 0;
    __syncthreads();

    const int nE4 = nE >> 2;               // b1 is 16B-aligned (cap1, EPB %4==0)
    const uint4* p4 = (const uint4*)(pairs1 + b1);
    for (int i = t; i < nE4; i += 256) {
        uint4 p = p4[i];
        atomicAdd(&hist[wv][p.x >> 23], 1);
        atomicAdd(&hist[wv][p.y >> 23], 1);
        atomicAdd(&hist[wv][p.z >> 23], 1);
        atomicAdd(&hist[wv][p.w >> 23], 1);
    }
    for (int i = (nE4 << 2) + t; i < nE; i += 256)
        atomicAdd(&hist[wv][pairs1[b1 + i] >> 23], 1);
    __syncthreads();
    if (t < 64) {
        int s = 0;
#pragma unroll
        for (int w = 0; w < 4; ++w) s += hist[w][t];
        tot[t] = s;
        scn[t] = s;
    }
    __syncthreads();
    for (int off = 1; off < 64; off <<= 1) {
        int v = (t < 64 && t >= off) ? scn[t - off] : 0;
        __syncthreads();
        if (t < 64) scn[t] += v;
        __syncthreads();
    }
    if (t < 64) {
        int h = tot[t];
        int gfb = cb * 64 + t;
        gbase[t] = h ? gfb * CAP2 + atomicAdd(&gcount2[gfb], h) : 0;
        int off = scn[t] - h;
#pragma unroll
        for (int w = 0; w < 4; ++w) { cur[w][t] = off; off += hist[w][t]; }
    }
    __syncthreads();
    for (int i = t; i < nE4; i += 256) {
        uint4 p = p4[i];
#pragma unroll
        for (int q = 0; q < 4; ++q) {
            unsigned pv = (&p.x)[q];
            int pos = atomicAdd(&cur[wv][pv >> 23], 1);
            sp[pos] = (pv & 0x1FFFFu) | (((pv >> 17) & 63u) << 18);
        }
    }
    for (int i = (nE4 << 2) + t; i < nE; i += 256) {
        unsigned pv = pairs1[b1 + i];
        int pos = atomicAdd(&cur[wv][pv >> 23], 1);
        sp[pos] = (pv & 0x1FFFFu) | (((pv >> 17) & 63u) << 18);
    }
    __syncthreads();
    const int lane = t & 63;
    for (int i = wv; i < 64; i += 4) {
        int end = scn[i];
        int st  = (i > 0) ? scn[i - 1] : 0;
        int len = end - st;
        if (len <= 0) continue;
        int gb = gbase[i];
        int fb0 = (cb * 64 + i) * CAP2;
        int rem = fb0 + CAP2 - gb;
        int wl = min(len, max(rem, 0));
        for (int k = lane; k < wl; k += 64)
            pairs2[gb + k] = sp[st + k];
    }
}

// K_FUSED: one block per 64-node fine bucket (proven 160 us version).
// Phase 1: per-node degree count + 64-entry scan in LDS. Phase 2: scatter
// src into LDS-sorted scol[]. Phase 3: register-accumulator aggregation
// (one wave per node; 8-edge group with ds_bpermute w-dedup).
__global__ void __launch_bounds__(512) k_fused(const unsigned* __restrict__ pairs,
                                               const int* __restrict__ gcount,
                                               const unsigned* __restrict__ h16,
                                               const float* __restrict__ a_src,
                                               const float* __restrict__ a_dst,
                                               const float* __restrict__ bias,
                                               float* __restrict__ out, int N) {
    __shared__ int cnt[AN];
    __shared__ int sc[AN];
    __shared__ int lcur[AN];
    __shared__ int lbeg[AN + 1];
    __shared__ unsigned scol[CAP2];
    const int b = blockIdx.x;
    const int t = threadIdx.x;
    const int n0 = b << ANSH;
    const unsigned base = (unsigned)b * (unsigned)CAP2;
    const int cb = min(gcount[b], CAP2);

    if (t < AN) cnt[t] = 0;
    __syncthreads();
    for (int j = t; j < cb; j += 512)
        atomicAdd(&cnt[pairs[base + j] >> 18], 1);
    __syncthreads();
    if (t < AN) sc[t] = cnt[t];
    __syncthreads();
    for (int off = 1; off < AN; off <<= 1) {
        int v = (t < AN && t >= off) ? sc[t - off] : 0;
        __syncthreads();
        if (t < AN) sc[t] += v;
        __syncthreads();
    }
    if (t < AN) {
        lbeg[t + 1] = sc[t];
        lcur[t] = sc[t] - cnt[t];
        if (t == 0) lbeg[0] = 0;
    }
    __syncthreads();
    for (int j = t; j < cb; j += 512) {
        unsigned pv = pairs[base + j];
        int pos = atomicAdd(&lcur[pv >> 18], 1);
        scol[pos] = pv & 0x3FFFFu;
    }
    __syncthreads();

    const int wv = t >> 6;          // wave 0..7
    const int lane = t & 63;
    const int hd = lane >> 3;       // this lane's head (channels 2*lane, 2*lane+1)
    const int hw = lane & 7;        // head of the (edge,head) pair lane computes
    const int bidx = hd * 4;        // bpermute byte index, edge slot 0

    for (int nl = wv; nl < AN; nl += 8) {
        const int node = n0 + nl;
        if (node >= N) break;       // uniform per wave (stride 8)
        const float adst_own = a_dst[(unsigned)node * 8u + (unsigned)hd];
        const float adst_hh  = a_dst[(unsigned)node * 8u + (unsigned)hw];
        const float wself = __expf(lrelu(a_src[(unsigned)node * 8u + (unsigned)hd] + adst_own));
        unsigned dself = h16[(unsigned)node * 64u + (unsigned)lane];
        float a0 = bf_lo(dself) * wself, a1 = bf_hi(dself) * wself;
        float b0 = 0.f, b1 = 0.f, c0 = 0.f, c1 = 0.f, e0 = 0.f, e1 = 0.f;
        float sA = wself, sB = 0.f, sC = 0.f, sD = 0.f;

        const int beg = lbeg[nl], end = lbeg[nl + 1];
        int j = beg;
        for (; j + 8 <= end; j += 8) {
            unsigned m0 = scol[j],     m1 = scol[j + 1], m2 = scol[j + 2], m3 = scol[j + 3];
            unsigned m4 = scol[j + 4], m5 = scol[j + 5], m6 = scol[j + 6], m7 = scol[j + 7];
            unsigned nP = scol[j + (lane >> 3)];   // pair's edge for this lane
            float wme = __expf(lrelu(a_src[nP * 8u + (unsigned)hw] + adst_hh));
            int wi = __float_as_int(wme);
            float w0 = __int_as_float(__builtin_amdgcn_ds_bpermute(bidx,       wi));
            float w1 = __int_as_float(__builtin_amdgcn_ds_bpermute(bidx + 32,  wi));
            float w2 = __int_as_float(__builtin_amdgcn_ds_bpermute(bidx + 64,  wi));
            float w3 = __int_as_float(__builtin_amdgcn_ds_bpermute(bidx + 96,  wi));
            float w4 = __int_as_float(__builtin_amdgcn_ds_bpermute(bidx + 128, wi));
            float w5 = __int_as_float(__builtin_amdgcn_ds_bpermute(bidx + 160, wi));
            float w6 = __int_as_float(__builtin_amdgcn_ds_bpermute(bidx + 192, wi));
            float w7 = __int_as_float(__builtin_amdgcn_ds_bpermute(bidx + 224, wi));
            unsigned d0 = h16[m0 * 64u + (unsigned)lane];
            unsigned d1 = h16[m1 * 64u + (unsigned)lane];
            unsigned d2 = h16[m2 * 64u + (unsigned)lane];
            unsigned d3 = h16[m3 * 64u + (unsigned)lane];
            unsigned d4 = h16[m4 * 64u + (unsigned)lane];
            unsigned d5 = h16[m5 * 64u + (unsigned)lane];
            unsigned d6 = h16[m6 * 64u + (unsigned)lane];
            unsigned d7 = h16[m7 * 64u + (unsigned)lane];
            a0 += bf_lo(d0) * w0; a1 += bf_hi(d0) * w0; sA += w0;
            b0 += bf_lo(d1) * w1; b1 += bf_hi(d1) * w1; sB += w1;
            c0 += bf_lo(d2) * w2; c1 += bf_hi(d2) * w2; sC += w2;
            e0 += bf_lo(d3) * w3; e1 += bf_hi(d3) * w3; sD += w3;
            a0 += bf_lo(d4) * w4; a1 += bf_hi(d4) * w4; sA += w4;
            b0 += bf_lo(d5) * w5; b1 += bf_hi(d5) * w5; sB += w5;
            c0 += bf_lo(d6) * w6; c1 += bf_hi(d6) * w6; sC += w6;
            e0 += bf_lo(d7) * w7; e1 += bf_hi(d7) * w7; sD += w7;
        }
        if (j + 4 <= end) {   // 4-wide tail (upper 32 lanes duplicate pair work)
            unsigned m0 = scol[j], m1 = scol[j + 1], m2 = scol[j + 2], m3 = scol[j + 3];
            unsigned nP = scol[j + ((lane >> 3) & 3)];
            float wme = __expf(lrelu(a_src[nP * 8u + (unsigned)hw] + adst_hh));
            int wi = __float_as_int(wme);
            float w0 = __int_as_float(__builtin_amdgcn_ds_bpermute(bidx,      wi));
            float w1 = __int_as_float(__builtin_amdgcn_ds_bpermute(bidx + 32, wi));
            float w2 = __int_as_float(__builtin_amdgcn_ds_bpermute(bidx + 64, wi));
            float w3 = __int_as_float(__builtin_amdgcn_ds_bpermute(bidx + 96, wi));
            unsigned d0 = h16[m0 * 64u + (unsigned)lane];
            unsigned d1 = h16[m1 * 64u + (unsigned)lane];
            unsigned d2 = h16[m2 * 64u + (unsigned)lane];
            unsigned d3 = h16[m3 * 64u + (unsigned)lane];
            a0 += bf_lo(d0) * w0; a1 += bf_hi(d0) * w0; sA += w0;
            b0 += bf_lo(d1) * w1; b1 += bf_hi(d1) * w1; sB += w1;
            c0 += bf_lo(d2) * w2; c1 += bf_hi(d2) * w2; sC += w2;
            e0 += bf_lo(d3) * w3; e1 += bf_hi(d3) * w3; sD += w3;
            j += 4;
        }
        for (; j < end; ++j) {
            unsigned mA = scol[j];
            float wA = __expf(lrelu(a_src[mA * 8u + (unsigned)hd] + adst_own));
            unsigned dA = h16[mA * 64u + (unsigned)lane];
            a0 += bf_lo(dA) * wA; a1 += bf_hi(dA) * wA; sA += wA;
        }
        const float s = sA + sB + sC + sD;
        const float inv = 1.f / (s + 1e-16f);
        const float acc0 = a0 + b0 + c0 + e0;
        const float acc1 = a1 + b1 + c1 + e1;
        const float2 bv = ((const float2*)bias)[lane];
        float2 o;
        o.x = acc0 * inv + bv.x;
        o.y = acc1 * inv + bv.y;
        ((float2*)out)[(unsigned)node * 64u + (unsigned)lane] = o;
    }
}

extern "C" void kernel_launch(void* const* d_in, const int* in_sizes, int n_in,
                              void* d_out, int out_size, void* d_ws, size_t ws_size,
                              hipStream_t stream) {
    const float* x       = (const float*)d_in[0];
    const int*   ei      = (const int*)d_in[1];
    const float* W       = (const float*)d_in[2];
    const float* att_src = (const float*)d_in[3];
    const float* att_dst = (const float*)d_in[4];
    const float* bias    = (const float*)d_in[5];
    float* out = (float*)d_out;

    const int N = in_sizes[0] / HC;
    const int E = in_sizes[1] / 2;
    const int B = (N + AMSK) >> ANSH;            // fine buckets (<= MAXB2)
    const int NB1 = (N + CBMSK) >> CB_SH;        // coarse buckets (<= MAXB1)
    const int nbin = (E + EPB - 1) / EPB;
    const int cap1 = (((E + NB1 - 1) / NB1) + 32768 + 3) & ~3;  // coarse capacity
    const int ch2 = (cap1 + EPB - 1) / EPB;      // level-2 chunks per coarse

    // ws: h16[N*64]u32 | a_src[N*8]f | a_dst[N*8]f | gcount1[64] |
    //     gcount2[MAXB2] | pairs1[NB1*cap1] | pairs2[B*CAP2]
    unsigned* h16 = (unsigned*)d_ws;
    float* a_src  = (float*)(h16 + (size_t)N * 64);
    float* a_dst  = a_src + (size_t)N * H;
    int* gcount1  = (int*)(a_dst + (size_t)N * H);
    int* gcount2  = gcount1 + MAXB1;
    unsigned* pairs1 = (unsigned*)(gcount2 + MAXB2);
    unsigned* pairs2 = pairs1 + (size_t)NB1 * (size_t)cap1;

    // Fork-join: binning chain on a side stream, concurrent with k1_gemm.
    // Event record/wait is capture-legal; statics init host-side.
    static hipStream_t s_side = nullptr;
    static hipEvent_t ev_fork = nullptr, ev_join = nullptr;
    if (s_side == nullptr) {
        (void)hipStreamCreateWithFlags(&s_side, hipStreamNonBlocking);
        (void)hipEventCreateWithFlags(&ev_fork, hipEventDisableTiming);
        (void)hipEventCreateWithFlags(&ev_join, hipEventDisableTiming);
    }
    const bool fork = (s_side != nullptr && ev_fork != nullptr && ev_join != nullptr);
    hipStream_t sb = fork ? s_side : stream;

    if (fork) {
        (void)hipEventRecord(ev_fork, stream);
        (void)hipStreamWaitEvent(sb, ev_fork, 0);
    }

    (void)hipMemsetAsync(gcount1, 0, (MAXB1 + MAXB2) * sizeof(int), sb);
    kb_bin1<<<nbin, 256, 0, sb>>>(ei, gcount1, pairs1, E, NB1, cap1);
    kb_bin2<<<NB1 * ch2, 256, 0, sb>>>(pairs1, gcount1, gcount2, pairs2,
                                       cap1, ch2);
    if (fork) (void)hipEventRecord(ev_join, sb);

    k1_gemm<<<(N + 63) / 64, 256, 0, stream>>>(x, W, att_src, att_dst,
                                               h16, a_src, a_dst, N);

    if (fork) (void)hipStreamWaitEvent(stream, ev_join, 0);

    k_fused<<<B, 512, 0, stream>>>(pairs2, gcount2, h16, a_src,
                                   a_dst, bias, out, N);
}

// Round 13
// 353.880 us; speedup vs baseline: 1.0612x; 1.0612x over previous
//
#include <hip/hip_runtime.h>
#include <hip/hip_bf16.h>

#define H 8
#define C 16
#define HC 128          // H*C
#define NEG 0.2f
#define XS_S 132        // LDS row stride (floats) for k1 x-tile

#define ANSH 6          // 64 nodes per fine aggregation bucket
#define AN 64
#define AMSK 63
#define CAP2 2560       // pairs2 capacity per fine bucket (mean 2048, +11 sigma)
#define MAXB2 2048      // fine bucket cap: N <= 131072
#define CB_SH 12        // 4096 nodes per coarse bucket
#define CBMSK 4095
#define MAXB1 64        // coarse bucket cap (src packs in 17b: N <= 131072)
#define EPB 4096        // edges per binning chunk (16 edges/thread @ 256 thr)

// exact: for x>=0 max returns x, for x<0 returns 0.2x  (2 VALU, no cndmask)
__device__ __forceinline__ float lrelu(float x) { return fmaxf(x, NEG * x); }

__device__ __forceinline__ unsigned pack_bf16(float a, float b) {
    union { __hip_bfloat16 h; unsigned short u; } ua, ub;
    ua.h = __float2bfloat16(a);
    ub.h = __float2bfloat16(b);
    return (unsigned)ua.u | ((unsigned)ub.u << 16);
}
__device__ __forceinline__ float bf_lo(unsigned d) { return __uint_as_float(d << 16); }
__device__ __forceinline__ float bf_hi(unsigned d) { return __uint_as_float(d & 0xffff0000u); }

// K1: h = x @ W, fp32 register-tiled GEMM, bf16-packed output (proven).
// Epilogue also computes a_src/a_dst (width-4 shfl reduce).
__global__ void __launch_bounds__(256) k1_gemm(const float* __restrict__ x,
                                               const float* __restrict__ W,
                                               const float* __restrict__ att_src,
                                               const float* __restrict__ att_dst,
                                               unsigned* __restrict__ h16,
                                               float* __restrict__ a_src,
                                               float* __restrict__ a_dst, int N) {
    __shared__ float xs[64 * XS_S];
    const int n0 = blockIdx.x * 64;
    const int t = threadIdx.x;
#pragma unroll
    for (int i = 0; i < 8; ++i) {
        int id = t + 256 * i;           // 2048 float4-chunks
        int r = id >> 5, kq = id & 31;
        int n = n0 + r;
        float4 v = (n < N) ? ((const float4*)x)[(size_t)n * 32 + kq]
                           : make_float4(0.f, 0.f, 0.f, 0.f);
        *(float4*)&xs[r * XS_S + kq * 4] = v;
    }
    __syncthreads();
    const int cg = t & 31;        // cols cg*4..+3
    const int r0 = (t >> 5) * 8;  // rows r0..r0+7
    float acc[8][4];
#pragma unroll
    for (int i = 0; i < 8; ++i)
#pragma unroll
        for (int j = 0; j < 4; ++j) acc[i][j] = 0.f;

#pragma unroll 4
    for (int k = 0; k < HC; ++k) {
        const float4 wv = ((const float4*)W)[k * 32 + cg];
        float wr[4] = {wv.x, wv.y, wv.z, wv.w};
#pragma unroll
        for (int i = 0; i < 8; ++i) {
            float xv = xs[(r0 + i) * XS_S + k];   // broadcast across cg lanes
#pragma unroll
            for (int j = 0; j < 4; ++j) acc[i][j] += xv * wr[j];
        }
    }
    const int fhd = cg >> 2;       // head owning this lane's 4 cols
    const int cq  = cg & 3;        // quarter within the head's 16 cols
#pragma unroll
    for (int i = 0; i < 8; ++i) {
        int n = n0 + r0 + i;
        if (n < N) {
            uint2 dv = make_uint2(pack_bf16(acc[i][0], acc[i][1]),
                                  pack_bf16(acc[i][2], acc[i][3]));
            *(uint2*)&h16[(size_t)n * 64 + cg * 2] = dv;
        }
        float ps = 0.f, pd = 0.f;
#pragma unroll
        for (int jj = 0; jj < 4; ++jj) {
            float hv = acc[i][jj];
            ps += hv * att_src[fhd * C + cq * 4 + jj];
            pd += hv * att_dst[fhd * C + cq * 4 + jj];
        }
        ps += __shfl_xor(ps, 1, 4); pd += __shfl_xor(pd, 1, 4);
        ps += __shfl_xor(ps, 2, 4); pd += __shfl_xor(pd, 2, 4);
        if (cq == 0 && n < N) {
            a_src[(unsigned)n * 8u + fhd] = ps;
            a_dst[(unsigned)n * 8u + fhd] = pd;
        }
    }
}

// KB_BIN1: coarse binning (25 buckets of 4096 nodes). SINGLE-READ version:
// 16 edges/thread held in registers (coalesced int4 loads), LDS histogram,
// 64-wide scan, global range reservation, then DIRECT global scatter via
// per-(wave,bucket) global cursors. No LDS staging, no copy-out, no second
// read of ei. Write streams: 25 regions/block, wave sub-ranges contiguous,
// lines stay hot in L2. Pack: src(17b) | (dst & 4095) << 17.
__global__ void __launch_bounds__(256) kb_bin1(const int* __restrict__ ei,
                                               int* __restrict__ gcount1,
                                               unsigned* __restrict__ pairs1,
                                               int E, int NB1, int cap1) {
    __shared__ int hist[4][MAXB1];
    __shared__ int cur[4][MAXB1];      // GLOBAL cursor per (wave,bucket)
    __shared__ int tot[MAXB1];
    __shared__ int scn[MAXB1];
    const int t = threadIdx.x;
    const int wv = t >> 6;
    const int e0 = blockIdx.x * EPB;
    const int nE = min(EPB, E - e0);
    ((int*)hist)[t] = 0;               // 4*64 == 256
    __syncthreads();

    // load up to 16 edges into registers (4 x int4 per thread, coalesced)
    const bool al4 = ((E & 3) == 0);
    const int nE4 = nE >> 2;
    int4 dreg[4], sreg[4];
    const int4* d4p = (const int4*)(ei + E + e0);
    const int4* s4p = (const int4*)(ei + e0);
#pragma unroll
    for (int j = 0; j < 4; ++j) {
        int idx = j * 256 + t;
        if (idx < nE4) {
            if (al4) { dreg[j] = d4p[idx]; sreg[j] = s4p[idx]; }
            else {
                int e = idx * 4;
                dreg[j] = make_int4(ei[E + e0 + e], ei[E + e0 + e + 1],
                                    ei[E + e0 + e + 2], ei[E + e0 + e + 3]);
                sreg[j] = make_int4(ei[e0 + e], ei[e0 + e + 1],
                                    ei[e0 + e + 2], ei[e0 + e + 3]);
            }
        }
    }
    int tlD = 0, tlS = -1;             // scalar tail (<=3 edges)
    {
        int tb = nE4 * 4 + t;
        if (tb < nE) { tlD = ei[E + e0 + tb]; tlS = ei[e0 + tb]; }
    }
#pragma unroll
    for (int j = 0; j < 4; ++j) {
        if (j * 256 + t < nE4) {
            atomicAdd(&hist[wv][dreg[j].x >> CB_SH], 1);
            atomicAdd(&hist[wv][dreg[j].y >> CB_SH], 1);
            atomicAdd(&hist[wv][dreg[j].z >> CB_SH], 1);
            atomicAdd(&hist[wv][dreg[j].w >> CB_SH], 1);
        }
    }
    if (tlS >= 0) atomicAdd(&hist[wv][tlD >> CB_SH], 1);
    __syncthreads();
    if (t < MAXB1) {
        int s = 0;
#pragma unroll
        for (int w = 0; w < 4; ++w) s += hist[w][t];
        tot[t] = s;
        scn[t] = s;                    // (scan kept for structural parity)
    }
    __syncthreads();
    for (int off = 1; off < MAXB1; off <<= 1) {
        int v = (t < MAXB1 && t >= off) ? scn[t - off] : 0;
        __syncthreads();
        if (t < MAXB1) scn[t] += v;
        __syncthreads();
    }
    if (t < MAXB1) {
        int h = tot[t];
        int gb = h ? t * cap1 + atomicAdd(&gcount1[t], h) : 0;
#pragma unroll
        for (int w = 0; w < 4; ++w) { cur[w][t] = gb; gb += hist[w][t]; }
    }
    __syncthreads();
#pragma unroll
    for (int j = 0; j < 4; ++j) {
        if (j * 256 + t < nE4) {
#pragma unroll
            for (int q = 0; q < 4; ++q) {
                int dst = (&dreg[j].x)[q], src = (&sreg[j].x)[q];
                int b = dst >> CB_SH;
                int pos = atomicAdd(&cur[wv][b], 1);
                if (pos < b * cap1 + cap1)
                    pairs1[pos] = (unsigned)src | ((unsigned)(dst & CBMSK) << 17);
            }
        }
    }
    if (tlS >= 0) {
        int b = tlD >> CB_SH;
        int pos = atomicAdd(&cur[wv][b], 1);
        if (pos < b * cap1 + cap1)
            pairs1[pos] = (unsigned)tlS | ((unsigned)(tlD & CBMSK) << 17);
    }
}

// KB_BIN2: fine binning within a coarse region, same single-read
// register-resident direct-scatter structure (64 fine buckets).
// Repack to src | ldst6<<18.
__global__ void __launch_bounds__(256) kb_bin2(const unsigned* __restrict__ pairs1,
                                               const int* __restrict__ gcount1,
                                               int* __restrict__ gcount2,
                                               unsigned* __restrict__ pairs2,
                                               int cap1, int ch2) {
    __shared__ int hist[4][64];
    __shared__ int cur[4][64];         // GLOBAL cursor per (wave,bucket)
    __shared__ int tot[64];
    const int cb = blockIdx.x / ch2;
    const int ci = blockIdx.x % ch2;
    const int c1 = min(gcount1[cb], cap1);
    const int e0 = ci * EPB;
    if (e0 >= c1) return;              // uniform exit
    const int nE = min(EPB, c1 - e0);
    const unsigned b1 = (unsigned)cb * (unsigned)cap1 + (unsigned)e0;
    const int t = threadIdx.x;
    const int wv = t >> 6;
    ((int*)hist)[t] = 0;               // 4*64 == 256
    __syncthreads();

    const int nE4 = nE >> 2;           // b1 is 16B-aligned (cap1, EPB %4==0)
    const uint4* p4 = (const uint4*)(pairs1 + b1);
    uint4 preg[4];
#pragma unroll
    for (int j = 0; j < 4; ++j) {
        int idx = j * 256 + t;
        if (idx < nE4) preg[j] = p4[idx];
    }
    unsigned tlP = 0; int tlV = 0;     // scalar tail (<=3 edges)
    {
        int tb = nE4 * 4 + t;
        if (tb < nE) { tlP = pairs1[b1 + tb]; tlV = 1; }
    }
#pragma unroll
    for (int j = 0; j < 4; ++j) {
        if (j * 256 + t < nE4) {
            atomicAdd(&hist[wv][preg[j].x >> 23], 1);
            atomicAdd(&hist[wv][preg[j].y >> 23], 1);
            atomicAdd(&hist[wv][preg[j].z >> 23], 1);
            atomicAdd(&hist[wv][preg[j].w >> 23], 1);
        }
    }
    if (tlV) atomicAdd(&hist[wv][tlP >> 23], 1);
    __syncthreads();
    if (t < 64) {
        int s = 0;
#pragma unroll
        for (int w = 0; w < 4; ++w) s += hist[w][t];
        tot[t] = s;
    }
    __syncthreads();
    if (t < 64) {
        int h = tot[t];
        int gfb = cb * 64 + t;
        int gb = h ? gfb * CAP2 + atomicAdd(&gcount2[gfb], h) : 0;
#pragma unroll
        for (int w = 0; w < 4; ++w) { cur[w][t] = gb; gb += hist[w][t]; }
    }
    __syncthreads();
#pragma unroll
    for (int j = 0; j < 4; ++j) {
        if (j * 256 + t < nE4) {
#pragma unroll
            for (int q = 0; q < 4; ++q) {
                unsigned pv = (&preg[j].x)[q];
                int fb = pv >> 23;
                int pos = atomicAdd(&cur[wv][fb], 1);
                if (pos < (cb * 64 + fb) * CAP2 + CAP2)
                    pairs2[pos] = (pv & 0x1FFFFu) | (((pv >> 17) & 63u) << 18);
            }
        }
    }
    if (tlV) {
        int fb = tlP >> 23;
        int pos = atomicAdd(&cur[wv][fb], 1);
        if (pos < (cb * 64 + fb) * CAP2 + CAP2)
            pairs2[pos] = (tlP & 0x1FFFFu) | (((tlP >> 17) & 63u) << 18);
    }
}

// K_FUSED: one block per 64-node fine bucket (proven 160 us version).
// Phase 1: per-node degree count + 64-entry scan in LDS. Phase 2: scatter
// src into LDS-sorted scol[]. Phase 3: register-accumulator aggregation
// (one wave per node; 8-edge group with ds_bpermute w-dedup).
__global__ void __launch_bounds__(512) k_fused(const unsigned* __restrict__ pairs,
                                               const int* __restrict__ gcount,
                                               const unsigned* __restrict__ h16,
                                               const float* __restrict__ a_src,
                                               const float* __restrict__ a_dst,
                                               const float* __restrict__ bias,
                                               float* __restrict__ out, int N) {
    __shared__ int cnt[AN];
    __shared__ int sc[AN];
    __shared__ int lcur[AN];
    __shared__ int lbeg[AN + 1];
    __shared__ unsigned scol[CAP2];
    const int b = blockIdx.x;
    const int t = threadIdx.x;
    const int n0 = b << ANSH;
    const unsigned base = (unsigned)b * (unsigned)CAP2;
    const int cb = min(gcount[b], CAP2);

    if (t < AN) cnt[t] = 0;
    __syncthreads();
    for (int j = t; j < cb; j += 512)
        atomicAdd(&cnt[pairs[base + j] >> 18], 1);
    __syncthreads();
    if (t < AN) sc[t] = cnt[t];
    __syncthreads();
    for (int off = 1; off < AN; off <<= 1) {
        int v = (t < AN && t >= off) ? sc[t - off] : 0;
        __syncthreads();
        if (t < AN) sc[t] += v;
        __syncthreads();
    }
    if (t < AN) {
        lbeg[t + 1] = sc[t];
        lcur[t] = sc[t] - cnt[t];
        if (t == 0) lbeg[0] = 0;
    }
    __syncthreads();
    for (int j = t; j < cb; j += 512) {
        unsigned pv = pairs[base + j];
        int pos = atomicAdd(&lcur[pv >> 18], 1);
        scol[pos] = pv & 0x3FFFFu;
    }
    __syncthreads();

    const int wv = t >> 6;          // wave 0..7
    const int lane = t & 63;
    const int hd = lane >> 3;       // this lane's head (channels 2*lane, 2*lane+1)
    const int hw = lane & 7;        // head of the (edge,head) pair lane computes
    const int bidx = hd * 4;        // bpermute byte index, edge slot 0

    for (int nl = wv; nl < AN; nl += 8) {
        const int node = n0 + nl;
        if (node >= N) break;       // uniform per wave (stride 8)
        const float adst_own = a_dst[(unsigned)node * 8u + (unsigned)hd];
        const float adst_hh  = a_dst[(unsigned)node * 8u + (unsigned)hw];
        const float wself = __expf(lrelu(a_src[(unsigned)node * 8u + (unsigned)hd] + adst_own));
        unsigned dself = h16[(unsigned)node * 64u + (unsigned)lane];
        float a0 = bf_lo(dself) * wself, a1 = bf_hi(dself) * wself;
        float b0 = 0.f, b1 = 0.f, c0 = 0.f, c1 = 0.f, e0 = 0.f, e1 = 0.f;
        float sA = wself, sB = 0.f, sC = 0.f, sD = 0.f;

        const int beg = lbeg[nl], end = lbeg[nl + 1];
        int j = beg;
        for (; j + 8 <= end; j += 8) {
            unsigned m0 = scol[j],     m1 = scol[j + 1], m2 = scol[j + 2], m3 = scol[j + 3];
            unsigned m4 = scol[j + 4], m5 = scol[j + 5], m6 = scol[j + 6], m7 = scol[j + 7];
            unsigned nP = scol[j + (lane >> 3)];   // pair's edge for this lane
            float wme = __expf(lrelu(a_src[nP * 8u + (unsigned)hw] + adst_hh));
            int wi = __float_as_int(wme);
            float w0 = __int_as_float(__builtin_amdgcn_ds_bpermute(bidx,       wi));
            float w1 = __int_as_float(__builtin_amdgcn_ds_bpermute(bidx + 32,  wi));
            float w2 = __int_as_float(__builtin_amdgcn_ds_bpermute(bidx + 64,  wi));
            float w3 = __int_as_float(__builtin_amdgcn_ds_bpermute(bidx + 96,  wi));
            float w4 = __int_as_float(__builtin_amdgcn_ds_bpermute(bidx + 128, wi));
            float w5 = __int_as_float(__builtin_amdgcn_ds_bpermute(bidx + 160, wi));
            float w6 = __int_as_float(__builtin_amdgcn_ds_bpermute(bidx + 192, wi));
            float w7 = __int_as_float(__builtin_amdgcn_ds_bpermute(bidx + 224, wi));
            unsigned d0 = h16[m0 * 64u + (unsigned)lane];
            unsigned d1 = h16[m1 * 64u + (unsigned)lane];
            unsigned d2 = h16[m2 * 64u + (unsigned)lane];
            unsigned d3 = h16[m3 * 64u + (unsigned)lane];
            unsigned d4 = h16[m4 * 64u + (unsigned)lane];
            unsigned d5 = h16[m5 * 64u + (unsigned)lane];
            unsigned d6 = h16[m6 * 64u + (unsigned)lane];
            unsigned d7 = h16[m7 * 64u + (unsigned)lane];
            a0 += bf_lo(d0) * w0; a1 += bf_hi(d0) * w0; sA += w0;
            b0 += bf_lo(d1) * w1; b1 += bf_hi(d1) * w1; sB += w1;
            c0 += bf_lo(d2) * w2; c1 += bf_hi(d2) * w2; sC += w2;
            e0 += bf_lo(d3) * w3; e1 += bf_hi(d3) * w3; sD += w3;
            a0 += bf_lo(d4) * w4; a1 += bf_hi(d4) * w4; sA += w4;
            b0 += bf_lo(d5) * w5; b1 += bf_hi(d5) * w5; sB += w5;
            c0 += bf_lo(d6) * w6; c1 += bf_hi(d6) * w6; sC += w6;
            e0 += bf_lo(d7) * w7; e1 += bf_hi(d7) * w7; sD += w7;
        }
        if (j + 4 <= end) {   // 4-wide tail (upper 32 lanes duplicate pair work)
            unsigned m0 = scol[j], m1 = scol[j + 1], m2 = scol[j + 2], m3 = scol[j + 3];
            unsigned nP = scol[j + ((lane >> 3) & 3)];
            float wme = __expf(lrelu(a_src[nP * 8u + (unsigned)hw] + adst_hh));
            int wi = __float_as_int(wme);
            float w0 = __int_as_float(__builtin_amdgcn_ds_bpermute(bidx,      wi));
            float w1 = __int_as_float(__builtin_amdgcn_ds_bpermute(bidx + 32, wi));
            float w2 = __int_as_float(__builtin_amdgcn_ds_bpermute(bidx + 64, wi));
            float w3 = __int_as_float(__builtin_amdgcn_ds_bpermute(bidx + 96, wi));
            unsigned d0 = h16[m0 * 64u + (unsigned)lane];
            unsigned d1 = h16[m1 * 64u + (unsigned)lane];
            unsigned d2 = h16[m2 * 64u + (unsigned)lane];
            unsigned d3 = h16[m3 * 64u + (unsigned)lane];
            a0 += bf_lo(d0) * w0; a1 += bf_hi(d0) * w0; sA += w0;
            b0 += bf_lo(d1) * w1; b1 += bf_hi(d1) * w1; sB += w1;
            c0 += bf_lo(d2) * w2; c1 += bf_hi(d2) * w2; sC += w2;
            e0 += bf_lo(d3) * w3; e1 += bf_hi(d3) * w3; sD += w3;
            j += 4;
        }
        for (; j < end; ++j) {
            unsigned mA = scol[j];
            float wA = __expf(lrelu(a_src[mA * 8u + (unsigned)hd] + adst_own));
            unsigned dA = h16[mA * 64u + (unsigned)lane];
            a0 += bf_lo(dA) * wA; a1 += bf_hi(dA) * wA; sA += wA;
        }
        const float s = sA + sB + sC + sD;
        const float inv = 1.f / (s + 1e-16f);
        const float acc0 = a0 + b0 + c0 + e0;
        const float acc1 = a1 + b1 + c1 + e1;
        const float2 bv = ((const float2*)bias)[lane];
        float2 o;
        o.x = acc0 * inv + bv.x;
        o.y = acc1 * inv + bv.y;
        ((float2*)out)[(unsigned)node * 64u + (unsigned)lane] = o;
    }
}

extern "C" void kernel_launch(void* const* d_in, const int* in_sizes, int n_in,
                              void* d_out, int out_size, void* d_ws, size_t ws_size,
                              hipStream_t stream) {
    const float* x       = (const float*)d_in[0];
    const int*   ei      = (const int*)d_in[1];
    const float* W       = (const float*)d_in[2];
    const float* att_src = (const float*)d_in[3];
    const float* att_dst = (const float*)d_in[4];
    const float* bias    = (const float*)d_in[5];
    float* out = (float*)d_out;

    const int N = in_sizes[0] / HC;
    const int E = in_sizes[1] / 2;
    const int B = (N + AMSK) >> ANSH;            // fine buckets (<= MAXB2)
    const int NB1 = (N + CBMSK) >> CB_SH;        // coarse buckets (<= MAXB1)
    const int nbin = (E + EPB - 1) / EPB;
    const int cap1 = (((E + NB1 - 1) / NB1) + 32768 + 3) & ~3;  // coarse capacity
    const int ch2 = (cap1 + EPB - 1) / EPB;      // level-2 chunks per coarse

    // ws: h16[N*64]u32 | a_src[N*8]f | a_dst[N*8]f | gcount1[64] |
    //     gcount2[MAXB2] | pairs1[NB1*cap1] | pairs2[B*CAP2]
    unsigned* h16 = (unsigned*)d_ws;
    float* a_src  = (float*)(h16 + (size_t)N * 64);
    float* a_dst  = a_src + (size_t)N * H;
    int* gcount1  = (int*)(a_dst + (size_t)N * H);
    int* gcount2  = gcount1 + MAXB1;
    unsigned* pairs1 = (unsigned*)(gcount2 + MAXB2);
    unsigned* pairs2 = pairs1 + (size_t)NB1 * (size_t)cap1;

    // Single stream (fork-join removed: measured benefit ~0 in R5/R11; this
    // gives clean per-dispatch attribution for the binning chain).
    (void)hipMemsetAsync(gcount1, 0, (MAXB1 + MAXB2) * sizeof(int), stream);
    kb_bin1<<<nbin, 256, 0, stream>>>(ei, gcount1, pairs1, E, NB1, cap1);
    kb_bin2<<<NB1 * ch2, 256, 0, stream>>>(pairs1, gcount1, gcount2, pairs2,
                                           cap1, ch2);
    k1_gemm<<<(N + 63) / 64, 256, 0, stream>>>(x, W, att_src, att_dst,
                                               h16, a_src, a_dst, N);
    k_fused<<<B, 512, 0, stream>>>(pairs2, gcount2, h16, a_src,
                                   a_dst, bias, out, N);
}